// Round 6
// baseline (3307.949 us; speedup 1.0000x reference)
//
#include <hip/hip_runtime.h>

typedef __attribute__((ext_vector_type(8))) short bf16x8;
typedef __attribute__((ext_vector_type(4))) float f32x4;
typedef unsigned short u16;
typedef unsigned int u32;

#define DT_ (10.0f / 9.0f)

__device__ __forceinline__ u16 f2bf(float f) {
  u32 u = __float_as_uint(f);
  u = (u + 0x7FFFu + ((u >> 16) & 1u)) >> 16;
  return (u16)u;
}

__device__ __forceinline__ float tanh_fast(float x) {
  float ax = fabsf(x);
  float e = __expf(-2.0f * ax);
  float t = (1.0f - e) / (1.0f + e);
  return (x < 0.0f) ? -t : t;
}

// Park cold RK state in AGPRs (otherwise idle half of the gfx950 register file).
__device__ __forceinline__ void ag_write(float& ag, float v) {
  asm volatile("v_accvgpr_write_b32 %0, %1" : "=a"(ag) : "v"(v));
}
__device__ __forceinline__ float ag_read(float ag) {
  float r;
  asm volatile("v_accvgpr_read_b32 %0, %1" : "=v"(r) : "a"(ag));
  return r;
}

// A/B fragment read from LDS: row-major [rows][K], row stride strideB bytes,
// XOR-swizzled with ((row&7)<<4). Lane l reads row0+(l&15), k = kE + (l>>4)*8 .. +8 (16B).
__device__ __forceinline__ bf16x8 frag_lds(const u16* Mb, int row0, int kE, int strideB) {
  const int l = threadIdx.x & 63;
  const int r = row0 + (l & 15);
  const int kb = (kE + ((l >> 4) << 3)) << 1;
  const int off = r * strideB + (kb ^ ((r & 7) << 4));
  return *(const bf16x8*)((const char*)Mb + off);
}

// B-operand fragment straight from global W^T (row-major [N][K], bf16), unswizzled.
__device__ __forceinline__ bf16x8 frag_glb(const u16* WT, int col0, int kE, int K) {
  const int l = threadIdx.x & 63;
  const int j = col0 + (l & 15);
  const int k = kE + ((l >> 4) << 3);
  return *(const bf16x8*)(WT + j * K + k);
}

// Stage piece: D[128 x NT*16] += A[128 x K] * B[K x NT*16]; 8 waves as 2(m) x 4(n);
// wave m-tile 64 rows (acc[4][NT]). NT=2 keeps live acc at 32 VGPRs.
template <int NT, int KST, bool BLDS>
__device__ __forceinline__ void gemm_stage(f32x4 (&acc)[4][NT],
                                           const u16* Ab, int aStrideB, int mb,
                                           const u16* Bp, int bK, int nb) {
#pragma unroll
  for (int mt = 0; mt < 4; ++mt)
#pragma unroll
    for (int nt = 0; nt < NT; ++nt)
      acc[mt][nt] = (f32x4){0.f, 0.f, 0.f, 0.f};
#pragma unroll
  for (int ks = 0; ks < KST; ++ks) {
    const int kE = ks * 32;
    bf16x8 av[4];
#pragma unroll
    for (int mt = 0; mt < 4; ++mt) av[mt] = frag_lds(Ab, mb + mt * 16, kE, aStrideB);
#pragma unroll
    for (int nt = 0; nt < NT; ++nt) {
      bf16x8 bv;
      if constexpr (BLDS) bv = frag_lds(Bp, nb + nt * 16, kE, 256);
      else                bv = frag_glb(Bp, nb + nt * 16, kE, bK);
#pragma unroll
      for (int mt = 0; mt < 4; ++mt)
        acc[mt][nt] = __builtin_amdgcn_mfma_f32_16x16x32_bf16(av[mt], bv, acc[mt][nt], 0, 0, 0);
    }
  }
}

// Write acc transposed (t^T) into Q: Q[col(feature)][node], row stride 256 B, swizzled.
template <int NT>
__device__ __forceinline__ void epi_T(const f32x4 (&acc)[4][NT], u16* Q, int nb, int mb, int lane) {
  const int l15 = lane & 15, lg = lane >> 4;
#pragma unroll
  for (int nt = 0; nt < NT; ++nt) {
    const int col = nb + nt * 16 + l15;
    const int swz = (col & 7) << 4;
    char* rowp = (char*)Q + col * 256;
#pragma unroll
    for (int mt = 0; mt < 4; ++mt) {
      f32x4 v = acc[mt][nt];
      const int r0 = mb + mt * 16 + (lg << 2);
      uint2 pk;
      pk.x = (u32)f2bf(v.x) | ((u32)f2bf(v.y) << 16);
      pk.y = (u32)f2bf(v.z) | ((u32)f2bf(v.w) << 16);
      *(uint2*)(rowp + ((r0 << 1) ^ swz)) = pk;
    }
  }
}

// Bias + tanh + write node-major into P (row stride 512 B, swizzled).
template <int NT>
__device__ __forceinline__ void epi_H(const f32x4 (&acc)[4][NT], u16* P, const float* bv,
                                      int nb, int mb, int lane) {
  const int l15 = lane & 15, lg = lane >> 4;
#pragma unroll
  for (int nt = 0; nt < NT; ++nt) {
    const int c = nb + nt * 16 + l15;
    const float bb = bv[nt];
#pragma unroll
    for (int mt = 0; mt < 4; ++mt) {
      f32x4 v = acc[mt][nt];
      const int r0 = mb + mt * 16 + (lg << 2);
#pragma unroll
      for (int e = 0; e < 4; ++e) {
        const int r = r0 + e;
        const float h = tanh_fast(v[e] + bb);
        *(u16*)((char*)P + r * 512 + ((c << 1) ^ ((r & 7) << 4))) = f2bf(h);
      }
    }
  }
}

// One f(z) evaluation; z (bf16, node-major, stride 256B, swizzled) in P on entry.
// RK state: yv in VGPRs; sv (k1+3k2[+3k3]) and vv (k1 then k1-k2) parked in AGPRs.
template <int E>
__device__ __forceinline__ void feval(int step,
    u16* P, u16* Q, const u16* As,
    const u16* __restrict__ W1T, const u16* __restrict__ W2T, const u16* __restrict__ W3T,
    const float (&b1v)[4], const float (&b2v)[4], const float (&b3v)[2],
    float (&yv)[32], float (&sv)[32], float (&vv)[32],
    float* __restrict__ out,
    int batch, int lane, int mb, int wn) {
  const int l15 = lane & 15, lg = lane >> 4;

  // stage 1: t1 = z @ W1   [M128 N256 K128] -> Q (t^T); two NT=2 passes
#pragma unroll
  for (int h = 0; h < 2; ++h) {
    f32x4 acc[4][2];
    gemm_stage<2, 4, false>(acc, P, 256, mb, W1T, 128, wn * 64 + h * 32);
    epi_T<2>(acc, Q, wn * 64 + h * 32, mb, lane);
  }
  __syncthreads();
  // stage 2: h1 = tanh(A @ t1 + b1) -> P node-major (stride 512)
#pragma unroll
  for (int h = 0; h < 2; ++h) {
    f32x4 acc[4][2];
    gemm_stage<2, 4, true>(acc, As, 256, mb, Q, 0, wn * 64 + h * 32);
    epi_H<2>(acc, P, &b1v[h * 2], wn * 64 + h * 32, mb, lane);
  }
  __syncthreads();
  // stage 3: t2 = h1 @ W2  [M128 N256 K256] -> Q (t^T)
#pragma unroll
  for (int h = 0; h < 2; ++h) {
    f32x4 acc[4][2];
    gemm_stage<2, 8, false>(acc, P, 512, mb, W2T, 256, wn * 64 + h * 32);
    epi_T<2>(acc, Q, wn * 64 + h * 32, mb, lane);
  }
  __syncthreads();
  // stage 4: h2 = tanh(A @ t2 + b2) -> P node-major
#pragma unroll
  for (int h = 0; h < 2; ++h) {
    f32x4 acc[4][2];
    gemm_stage<2, 4, true>(acc, As, 256, mb, Q, 0, wn * 64 + h * 32);
    epi_H<2>(acc, P, &b2v[h * 2], wn * 64 + h * 32, mb, lane);
  }
  __syncthreads();
  { // stage 5: t3 = h2 @ W3  [M128 N128 K256] -> Q rows 0..127
    f32x4 acc[4][2];
    gemm_stage<2, 8, false>(acc, P, 512, mb, W3T, 256, wn * 32);
    epi_T<2>(acc, Q, wn * 32, mb, lane);
  }
  __syncthreads();
  { // stage 6: k = A @ t3 + b3 [M128 N128 K128] + fused RK epilogue
    f32x4 acc[4][2];
    gemm_stage<2, 4, true>(acc, As, 256, mb, Q, 0, wn * 32);
#pragma unroll
    for (int nt = 0; nt < 2; ++nt) {
      const int c = wn * 32 + nt * 16 + l15;
      const float bb = b3v[nt];
#pragma unroll
      for (int mt = 0; mt < 4; ++mt) {
        f32x4 v = acc[mt][nt];
        const int r0 = mb + mt * 16 + (lg << 2);
#pragma unroll
        for (int e = 0; e < 4; ++e) {
          const int r = r0 + e;
          const int idx = (mt * 2 + nt) * 4 + e;
          const float kv = v[e] + bb;
          float z;
          if constexpr (E == 1) {
            ag_write(vv[idx], kv);  // k1
            z = yv[idx] + (DT_ * (1.0f / 3.0f)) * kv;
          } else if constexpr (E == 2) {
            const float k1 = ag_read(vv[idx]);
            ag_write(sv[idx], k1 + 3.0f * kv);
            ag_write(vv[idx], k1 - kv);
            z = yv[idx] + DT_ * (kv - k1 * (1.0f / 3.0f));
          } else if constexpr (E == 3) {
            z = yv[idx] + DT_ * (ag_read(vv[idx]) + kv);
            ag_write(sv[idx], ag_read(sv[idx]) + 3.0f * kv);
          } else {
            const float yn = yv[idx] + (DT_ * 0.125f) * (ag_read(sv[idx]) + kv);
            yv[idx] = yn;
            out[batch * 163840 + r * 1280 + (step + 1) * 128 + c] = yn;
            z = yn;
          }
          // z for the next eval -> P (node-major, stride 256, swizzled)
          *(u16*)((char*)P + r * 256 + ((c << 1) ^ ((r & 7) << 4))) = f2bf(z);
        }
      }
    }
  }
  __syncthreads();
}

__global__ __launch_bounds__(512, 2)             // 8-wave block, 1 block/CU -> 2 waves/EU
__attribute__((amdgpu_waves_per_eu(2, 2)))
void ode_main(
    const u16* __restrict__ Aswz,
    const u16* __restrict__ W1T, const u16* __restrict__ W2T, const u16* __restrict__ W3T,
    const float* __restrict__ b1, const float* __restrict__ b2, const float* __restrict__ b3,
    const float* __restrict__ x,
    float* __restrict__ out) {
  __shared__ u16 P[32768];   // 64 KB: activations node-major / z
  __shared__ u16 Q[32768];   // 64 KB: transposed intermediates t^T
  __shared__ u16 As[16384];  // 32 KB: normalized adjacency, pre-swizzled
  const int tid = threadIdx.x;
  const int lane = tid & 63;
  const int wid = tid >> 6;
  const int wm = wid >> 2, wn = wid & 3;
  const int mb = wm * 64;
  const int l15 = lane & 15, lg = lane >> 4;
  const int batch = blockIdx.x;

  { // stage adjacency into LDS (pre-swizzled in ws -> linear copy); 2048 uint4
    const uint4* s = (const uint4*)Aswz;
    uint4* d = (uint4*)As;
#pragma unroll
    for (int i = 0; i < 4; ++i) d[tid + i * 512] = s[tid + i * 512];
  }

  // RK state: y in VGPRs; s,v parked in AGPRs (cold storage, touched once per feval).
  float yv[32], sv[32], vv[32];
#pragma unroll
  for (int mt = 0; mt < 4; ++mt)
#pragma unroll
    for (int nt = 0; nt < 2; ++nt)
#pragma unroll
      for (int e = 0; e < 4; ++e) {
        const int r = mb + mt * 16 + (lg << 2) + e;
        const int c = wn * 32 + nt * 16 + l15;
        const int idx = (mt * 2 + nt) * 4 + e;
        const float v = x[((batch * 128 + r) * 12 + 11) * 128 + c];
        yv[idx] = v;
        ag_write(sv[idx], 0.f);
        ag_write(vv[idx], 0.f);
        out[batch * 163840 + r * 1280 + c] = v;
        *(u16*)((char*)P + r * 256 + ((c << 1) ^ ((r & 7) << 4))) = f2bf(v);
      }

  // bias registers (per-lane columns)
  float b1v[4], b2v[4], b3v[2];
#pragma unroll
  for (int nt = 0; nt < 4; ++nt) {
    b1v[nt] = b1[wn * 64 + nt * 16 + l15];
    b2v[nt] = b2[wn * 64 + nt * 16 + l15];
  }
#pragma unroll
  for (int nt = 0; nt < 2; ++nt) b3v[nt] = b3[wn * 32 + nt * 16 + l15];
  __syncthreads();

  for (int s = 0; s < 9; ++s) {
    feval<1>(s, P, Q, As, W1T, W2T, W3T, b1v, b2v, b3v, yv, sv, vv, out, batch, lane, mb, wn);
    feval<2>(s, P, Q, As, W1T, W2T, W3T, b1v, b2v, b3v, yv, sv, vv, out, batch, lane, mb, wn);
    feval<3>(s, P, Q, As, W1T, W2T, W3T, b1v, b2v, b3v, yv, sv, vv, out, batch, lane, mb, wn);
    feval<4>(s, P, Q, As, W1T, W2T, W3T, b1v, b2v, b3v, yv, sv, vv, out, batch, lane, mb, wn);
  }
}

// ---- prep kernels ----

__global__ void prep_adj_k(const float* __restrict__ adjw, u16* __restrict__ Aswz) {
  const int n = blockIdx.x;
  const int m = threadIdx.x;  // 128 threads = 2 waves
  const float w = adjw[n * 128 + m];
  const float sg = 1.0f / (1.0f + __expf(-w));
  float s = sg;
#pragma unroll
  for (int o = 1; o < 64; o <<= 1) s += __shfl_xor(s, o);
  __shared__ float red[2];
  if ((m & 63) == 0) red[m >> 6] = s;
  __syncthreads();
  const float deg = fmaxf(red[0] + red[1], 1.0f);
  const float v = sg / deg;
  *(u16*)((char*)Aswz + n * 256 + ((m << 1) ^ ((n & 7) << 4))) = f2bf(v);
}

__global__ void prep_w_k(const float* __restrict__ W1, const float* __restrict__ W2,
                         const float* __restrict__ W3,
                         u16* __restrict__ W1T, u16* __restrict__ W2T, u16* __restrict__ W3T) {
  const int i = blockIdx.x * 256 + threadIdx.x;
  if (i < 32768) {
    W1T[i] = f2bf(W1[(i & 127) * 256 + (i >> 7)]);  // W1T[hid][f] = W1[f][hid]
    W3T[i] = f2bf(W3[(i & 255) * 128 + (i >> 8)]);  // W3T[f][hid] = W3[hid][f]
  }
  if (i < 65536) W2T[i] = f2bf(W2[(i & 255) * 256 + (i >> 8)]);  // W2T[h2][h1] = W2[h1][h2]
}

extern "C" void kernel_launch(void* const* d_in, const int* in_sizes, int n_in,
                              void* d_out, int out_size, void* d_ws, size_t ws_size,
                              hipStream_t stream) {
  const float* x    = (const float*)d_in[0];
  const float* adjw = (const float*)d_in[1];
  const float* W1   = (const float*)d_in[2];
  const float* b1   = (const float*)d_in[3];
  const float* W2   = (const float*)d_in[4];
  const float* b2   = (const float*)d_in[5];
  const float* W3   = (const float*)d_in[6];
  const float* b3   = (const float*)d_in[7];
  float* out = (float*)d_out;

  u16* Aswz = (u16*)d_ws;
  u16* W1T = Aswz + 16384;
  u16* W2T = W1T + 32768;
  u16* W3T = W2T + 65536;

  prep_adj_k<<<128, 128, 0, stream>>>(adjw, Aswz);
  prep_w_k<<<256, 256, 0, stream>>>(W1, W2, W3, W1T, W2T, W3T);
  ode_main<<<128, 512, 0, stream>>>(Aswz, W1T, W2T, W3T, b1, b2, b3, x, out);
}

// Round 7
// 1796.238 us; speedup vs baseline: 1.8416x; 1.8416x over previous
//
#include <hip/hip_runtime.h>

typedef __attribute__((ext_vector_type(8))) short bf16x8;
typedef __attribute__((ext_vector_type(4))) float f32x4;
typedef unsigned short u16;
typedef unsigned int u32;

#define DT_ (10.0f / 9.0f)

__device__ __forceinline__ u16 f2bf(float f) {
  u32 u = __float_as_uint(f);
  u = (u + 0x7FFFu + ((u >> 16) & 1u)) >> 16;
  return (u16)u;
}

__device__ __forceinline__ float tanh_fast(float x) {
  float ax = fabsf(x);
  float e = __expf(-2.0f * ax);
  float t = (1.0f - e) / (1.0f + e);
  return (x < 0.0f) ? -t : t;
}

// A/B fragment read from LDS: row-major [rows][K], row stride strideB bytes,
// XOR-swizzled with ((row&7)<<4). Lane l reads row0+(l&15), k = kE + (l>>4)*8 .. +8 (16B).
__device__ __forceinline__ bf16x8 frag_lds(const u16* Mb, int row0, int kE, int strideB) {
  const int l = threadIdx.x & 63;
  const int r = row0 + (l & 15);
  const int kb = (kE + ((l >> 4) << 3)) << 1;
  const int off = r * strideB + (kb ^ ((r & 7) << 4));
  return *(const bf16x8*)((const char*)Mb + off);
}

// B-operand fragment straight from global W^T (row-major [N][K], bf16), unswizzled.
__device__ __forceinline__ bf16x8 frag_glb(const u16* WT, int col0, int kE, int K) {
  const int l = threadIdx.x & 63;
  const int j = col0 + (l & 15);
  const int k = kE + ((l >> 4) << 3);
  return *(const bf16x8*)(WT + j * K + k);
}

// Single-column-block pass: D[128 x 16] at col block nb; 8 waves as 2(m) x 4(n);
// wave m-tile 64 rows. acc[4] = 16 VGPRs live (NT=1 keeps peak pressure < 128).
template <int KST, bool BLDS>
__device__ __forceinline__ void gemm1(f32x4 (&acc)[4], const u16* Ab, int aStrideB, int mb,
                                      const u16* Bp, int bK, int nb) {
#pragma unroll
  for (int mt = 0; mt < 4; ++mt) acc[mt] = (f32x4){0.f, 0.f, 0.f, 0.f};
#pragma unroll
  for (int ks = 0; ks < KST; ++ks) {
    const int kE = ks * 32;
    bf16x8 bv;
    if constexpr (BLDS) bv = frag_lds(Bp, nb, kE, 256);
    else                bv = frag_glb(Bp, nb, kE, bK);
    bf16x8 av[4];
#pragma unroll
    for (int mt = 0; mt < 4; ++mt) av[mt] = frag_lds(Ab, mb + mt * 16, kE, aStrideB);
#pragma unroll
    for (int mt = 0; mt < 4; ++mt)
      acc[mt] = __builtin_amdgcn_mfma_f32_16x16x32_bf16(av[mt], bv, acc[mt], 0, 0, 0);
  }
}

// Write acc transposed (t^T) into Q: Q[col(feature)][node], row stride 256 B, swizzled.
__device__ __forceinline__ void epi_T1(const f32x4 (&acc)[4], u16* Q, int col, int mb, int lane) {
  const int l15 = lane & 15, lg = lane >> 4;
  const int c = col + l15;
  const int swz = (c & 7) << 4;
  char* rowp = (char*)Q + c * 256;
#pragma unroll
  for (int mt = 0; mt < 4; ++mt) {
    f32x4 v = acc[mt];
    const int r0 = mb + mt * 16 + (lg << 2);
    uint2 pk;
    pk.x = (u32)f2bf(v.x) | ((u32)f2bf(v.y) << 16);
    pk.y = (u32)f2bf(v.z) | ((u32)f2bf(v.w) << 16);
    *(uint2*)(rowp + ((r0 << 1) ^ swz)) = pk;
  }
}

// Bias (from global) + tanh + write node-major into P (row stride 512 B, swizzled).
__device__ __forceinline__ void epi_H1(const f32x4 (&acc)[4], u16* P, const float* __restrict__ b,
                                       int col, int mb, int lane) {
  const int l15 = lane & 15, lg = lane >> 4;
  const int c = col + l15;
  const float bb = b[c];
#pragma unroll
  for (int mt = 0; mt < 4; ++mt) {
    f32x4 v = acc[mt];
    const int r0 = mb + mt * 16 + (lg << 2);
#pragma unroll
    for (int e = 0; e < 4; ++e) {
      const int r = r0 + e;
      const float h = tanh_fast(v[e] + bb);
      *(u16*)((char*)P + r * 512 + ((c << 1) ^ ((r & 7) << 4))) = f2bf(h);
    }
  }
}

// One f(z) evaluation; z (bf16, node-major, stride 256B, swizzled) in P on entry.
// RK state restructured to TWO persistent arrays:
//  after E1: a1 = y, a2 = k1
//  after E2: a1 = V = y + dt/8(k1+3k2), a2 = U = y + dt(k1-k2)
//  after E3: a1 = W = V + 3dt/8 k3     (a2 dead)
//  after E4: a1 = yn
template <int E>
__device__ __forceinline__ void feval(int step,
    u16* P, u16* Q, const u16* As,
    const u16* __restrict__ W1T, const u16* __restrict__ W2T, const u16* __restrict__ W3T,
    const float* __restrict__ b1, const float* __restrict__ b2, const float* __restrict__ b3,
    float (&a1)[32], float (&a2)[32],
    float* __restrict__ out,
    int batch, int lane, int mb, int wn) {
  const int l15 = lane & 15, lg = lane >> 4;

  // stage 1: t1 = z @ W1   [M128 N256 K128] -> Q (t^T)
#pragma unroll 1
  for (int p = 0; p < 4; ++p) {
    f32x4 acc[4];
    gemm1<4, false>(acc, P, 256, mb, W1T, 128, wn * 64 + p * 16);
    epi_T1(acc, Q, wn * 64 + p * 16, mb, lane);
  }
  __syncthreads();
  // stage 2: h1 = tanh(A @ t1 + b1) -> P node-major (stride 512)
#pragma unroll 1
  for (int p = 0; p < 4; ++p) {
    f32x4 acc[4];
    gemm1<4, true>(acc, As, 256, mb, Q, 0, wn * 64 + p * 16);
    epi_H1(acc, P, b1, wn * 64 + p * 16, mb, lane);
  }
  __syncthreads();
  // stage 3: t2 = h1 @ W2  [M128 N256 K256] -> Q (t^T)
#pragma unroll 1
  for (int p = 0; p < 4; ++p) {
    f32x4 acc[4];
    gemm1<8, false>(acc, P, 512, mb, W2T, 256, wn * 64 + p * 16);
    epi_T1(acc, Q, wn * 64 + p * 16, mb, lane);
  }
  __syncthreads();
  // stage 4: h2 = tanh(A @ t2 + b2) -> P node-major
#pragma unroll 1
  for (int p = 0; p < 4; ++p) {
    f32x4 acc[4];
    gemm1<4, true>(acc, As, 256, mb, Q, 0, wn * 64 + p * 16);
    epi_H1(acc, P, b2, wn * 64 + p * 16, mb, lane);
  }
  __syncthreads();
  // stage 5: t3 = h2 @ W3  [M128 N128 K256] -> Q rows 0..127
#pragma unroll 1
  for (int p = 0; p < 2; ++p) {
    f32x4 acc[4];
    gemm1<8, false>(acc, P, 512, mb, W3T, 256, wn * 32 + p * 16);
    epi_T1(acc, Q, wn * 32 + p * 16, mb, lane);
  }
  __syncthreads();
  // stage 6: k = A @ t3 + b3 [M128 N128 K128] + fused RK epilogue (MUST stay unrolled:
  // a1/a2 are register arrays -> compile-time indices only)
#pragma unroll
  for (int p = 0; p < 2; ++p) {
    f32x4 acc[4];
    gemm1<4, true>(acc, As, 256, mb, Q, 0, wn * 32 + p * 16);
    const int c = wn * 32 + p * 16 + l15;
    const float bb = b3[c];
#pragma unroll
    for (int mt = 0; mt < 4; ++mt) {
      f32x4 v = acc[mt];
      const int r0 = mb + mt * 16 + (lg << 2);
#pragma unroll
      for (int e = 0; e < 4; ++e) {
        const int r = r0 + e;
        const int idx = (p * 4 + mt) * 4 + e;
        const float kv = v[e] + bb;
        float z;
        if constexpr (E == 1) {
          a2[idx] = kv;                               // k1
          z = a1[idx] + (DT_ * (1.0f / 3.0f)) * kv;
        } else if constexpr (E == 2) {
          const float k1 = a2[idx];
          const float y = a1[idx];
          z = y + DT_ * (kv - k1 * (1.0f / 3.0f));
          a2[idx] = y + DT_ * (k1 - kv);              // U
          a1[idx] = y + (DT_ * 0.125f) * (k1 + 3.0f * kv);  // V
        } else if constexpr (E == 3) {
          z = a2[idx] + DT_ * kv;                     // z4 = U + dt*k3
          a1[idx] += (DT_ * 0.375f) * kv;             // W = V + 3dt/8*k3
        } else {
          const float yn = a1[idx] + (DT_ * 0.125f) * kv;
          a1[idx] = yn;
          out[batch * 163840 + r * 1280 + (step + 1) * 128 + c] = yn;
          z = yn;
        }
        // z for the next eval -> P (node-major, stride 256, swizzled)
        *(u16*)((char*)P + r * 256 + ((c << 1) ^ ((r & 7) << 4))) = f2bf(z);
      }
    }
  }
  __syncthreads();
}

__global__ __launch_bounds__(512, 2)             // 8-wave block, 1 block/CU -> 2 waves/EU
__attribute__((amdgpu_waves_per_eu(2, 2)))
void ode_main(
    const u16* __restrict__ Aswz,
    const u16* __restrict__ W1T, const u16* __restrict__ W2T, const u16* __restrict__ W3T,
    const float* __restrict__ b1, const float* __restrict__ b2, const float* __restrict__ b3,
    const float* __restrict__ x,
    float* __restrict__ out) {
  __shared__ u16 P[32768];   // 64 KB: activations node-major / z
  __shared__ u16 Q[32768];   // 64 KB: transposed intermediates t^T
  __shared__ u16 As[16384];  // 32 KB: normalized adjacency, pre-swizzled
  const int tid = threadIdx.x;
  const int lane = tid & 63;
  const int wid = tid >> 6;
  const int wm = wid >> 2, wn = wid & 3;
  const int mb = wm * 64;
  const int l15 = lane & 15, lg = lane >> 4;
  const int batch = blockIdx.x;

  { // stage adjacency into LDS (pre-swizzled in ws -> linear copy); 2048 uint4
    const uint4* s = (const uint4*)Aswz;
    uint4* d = (uint4*)As;
#pragma unroll
    for (int i = 0; i < 4; ++i) d[tid + i * 512] = s[tid + i * 512];
  }

  // RK state: 2 persistent register arrays (a1 = y; a2 scratch for k1/U).
  float a1[32], a2[32];
#pragma unroll
  for (int p = 0; p < 2; ++p)
#pragma unroll
    for (int mt = 0; mt < 4; ++mt)
#pragma unroll
      for (int e = 0; e < 4; ++e) {
        const int r = mb + mt * 16 + (lg << 2) + e;
        const int c = wn * 32 + p * 16 + l15;
        const int idx = (p * 4 + mt) * 4 + e;
        const float v = x[((batch * 128 + r) * 12 + 11) * 128 + c];
        a1[idx] = v;
        a2[idx] = 0.f;
        out[batch * 163840 + r * 1280 + c] = v;
        *(u16*)((char*)P + r * 256 + ((c << 1) ^ ((r & 7) << 4))) = f2bf(v);
      }
  __syncthreads();

  for (int s = 0; s < 9; ++s) {
    feval<1>(s, P, Q, As, W1T, W2T, W3T, b1, b2, b3, a1, a2, out, batch, lane, mb, wn);
    feval<2>(s, P, Q, As, W1T, W2T, W3T, b1, b2, b3, a1, a2, out, batch, lane, mb, wn);
    feval<3>(s, P, Q, As, W1T, W2T, W3T, b1, b2, b3, a1, a2, out, batch, lane, mb, wn);
    feval<4>(s, P, Q, As, W1T, W2T, W3T, b1, b2, b3, a1, a2, out, batch, lane, mb, wn);
  }
}

// ---- prep kernels ----

__global__ void prep_adj_k(const float* __restrict__ adjw, u16* __restrict__ Aswz) {
  const int n = blockIdx.x;
  const int m = threadIdx.x;  // 128 threads = 2 waves
  const float w = adjw[n * 128 + m];
  const float sg = 1.0f / (1.0f + __expf(-w));
  float s = sg;
#pragma unroll
  for (int o = 1; o < 64; o <<= 1) s += __shfl_xor(s, o);
  __shared__ float red[2];
  if ((m & 63) == 0) red[m >> 6] = s;
  __syncthreads();
  const float deg = fmaxf(red[0] + red[1], 1.0f);
  const float v = sg / deg;
  *(u16*)((char*)Aswz + n * 256 + ((m << 1) ^ ((n & 7) << 4))) = f2bf(v);
}

__global__ void prep_w_k(const float* __restrict__ W1, const float* __restrict__ W2,
                         const float* __restrict__ W3,
                         u16* __restrict__ W1T, u16* __restrict__ W2T, u16* __restrict__ W3T) {
  const int i = blockIdx.x * 256 + threadIdx.x;
  if (i < 32768) {
    W1T[i] = f2bf(W1[(i & 127) * 256 + (i >> 7)]);  // W1T[hid][f] = W1[f][hid]
    W3T[i] = f2bf(W3[(i & 255) * 128 + (i >> 8)]);  // W3T[f][hid] = W3[hid][f]
  }
  if (i < 65536) W2T[i] = f2bf(W2[(i & 255) * 256 + (i >> 8)]);  // W2T[h2][h1] = W2[h1][h2]
}

extern "C" void kernel_launch(void* const* d_in, const int* in_sizes, int n_in,
                              void* d_out, int out_size, void* d_ws, size_t ws_size,
                              hipStream_t stream) {
  const float* x    = (const float*)d_in[0];
  const float* adjw = (const float*)d_in[1];
  const float* W1   = (const float*)d_in[2];
  const float* b1   = (const float*)d_in[3];
  const float* W2   = (const float*)d_in[4];
  const float* b2   = (const float*)d_in[5];
  const float* W3   = (const float*)d_in[6];
  const float* b3   = (const float*)d_in[7];
  float* out = (float*)d_out;

  u16* Aswz = (u16*)d_ws;
  u16* W1T = Aswz + 16384;
  u16* W2T = W1T + 32768;
  u16* W3T = W2T + 65536;

  prep_adj_k<<<128, 128, 0, stream>>>(adjw, Aswz);
  prep_w_k<<<256, 256, 0, stream>>>(W1, W2, W3, W1T, W2T, W3T);
  ode_main<<<128, 512, 0, stream>>>(Aswz, W1T, W2T, W3T, b1, b2, b3, x, out);
}